// Round 4
// baseline (201.670 us; speedup 1.0000x reference)
//
#include <hip/hip_runtime.h>
#include <stdint.h>

// Grossberg shunting ODE, 127 Euler steps, BATCH=32768, N=17.
// 8 lanes per item: lanes 0-3 = W_pos (E side) row-blocks {0-4,5-8,9-12,13-16},
// lanes 4-7 = W_neg (I side) same rows. W packed f16 pairs, 45 u32/lane.
// Uniform (divergence-free) transform; cross-lane via ds_swizzle immediates.
// 4096 waves = 4/SIMD -> __launch_bounds__(256,4), VGPR<=128, no AGPR moves.

typedef _Float16 h2 __attribute__((ext_vector_type(2)));
typedef __fp16 h2raw __attribute__((ext_vector_type(2)));

static constexpr int BATCH = 32768;
static constexpr int NN = 17;
static constexpr int TT = 128;

__device__ __forceinline__ uint32_t pk(float a, float b) {
    h2raw h = __builtin_amdgcn_cvt_pkrtz(a, b);
    return __builtin_bit_cast(uint32_t, h);
}
__device__ __forceinline__ float dot2(uint32_t a, uint32_t b, float c) {
#if __has_builtin(__builtin_amdgcn_fdot2)
    return __builtin_amdgcn_fdot2(__builtin_bit_cast(h2, a),
                                  __builtin_bit_cast(h2, b), c, false);
#else
    h2 ah = __builtin_bit_cast(h2, a), bh = __builtin_bit_cast(h2, b);
    return c + (float)ah.x * (float)bh.x + (float)ah.y * (float)bh.y;
#endif
}
__device__ __forceinline__ float lo16(uint32_t u) {
    h2 h = __builtin_bit_cast(h2, u); return (float)h.x;
}
__device__ __forceinline__ float hi16(uint32_t u) {
    h2 h = __builtin_bit_cast(h2, u); return (float)h.y;
}
template <int IMM>
__device__ __forceinline__ uint32_t swz(uint32_t v) {
    return (uint32_t)__builtin_amdgcn_ds_swizzle((int)v, IMM);
}
template <int IMM>
__device__ __forceinline__ float swzf(float v) {
    return __builtin_bit_cast(float,
        (uint32_t)__builtin_amdgcn_ds_swizzle(
            (int)__builtin_bit_cast(uint32_t, v), IMM));
}

// ds_swizzle BitMode imms: src_lane = ((lane & and) | or) ^ xor
// broadcast lane k within octet: and=0x18, or=k  -> (k<<5)|0x18
// partner exchange lane^4:       and=0x1F, xor=4 -> 0x101F
static constexpr int SWZ_B0 = 0x18, SWZ_B1 = 0x38, SWZ_B2 = 0x58, SWZ_B3 = 0x78;
static constexpr int SWZ_X4 = 0x101F;

__global__ __launch_bounds__(256, 4) void hotco_kernel(
    const float* __restrict__ state0,
    const float* __restrict__ Wpos,
    const float* __restrict__ Wneg,
    const float* __restrict__ feas,
    const float* __restrict__ P,
    const float* __restrict__ t_eval,
    float* __restrict__ out)
{
    const int tid = blockIdx.x * blockDim.x + threadIdx.x;
    const int lq = tid & 7;        // octet lane
    const int b  = tid >> 3;
    const int l4 = lq & 3;         // row-block id
    const bool isE   = lq < 4;     // E side (W_pos) vs I side (W_neg)
    const bool isActs = (l4 == 2);
    const bool isLat  = (lq == 6); // acts I-side gets lateral add

    // row block: l4=0 -> rows 0-4 (needs), 1 -> 5-8 (needs), 2 -> 9-12 (acts), 3 -> 13-16 (vals)
    const int base = (l4 == 0) ? 0 : (4 * l4 + 1);
    const int nrows = (l4 == 0) ? 5 : 4;

    // pair grouping: (0,1)(2,3)(4,-)(5,6)(7,8)(9,10)(11,12)(13,14)(15,16)
    constexpr int pA[9] = {0, 2, 4, 5, 7, 9, 11, 13, 15};
    constexpr int pB[9] = {1, 3, -1, 6, 8, 10, 12, 14, 16};

    // ---- W (own side only) into registers, packed f16 ----
    uint32_t w[5][9];
    {
        const float* Wb = (isE ? Wpos : Wneg) + (size_t)b * (NN * NN);
#pragma unroll
        for (int t = 0; t < 5; ++t) {
            if (t < nrows) {
                const float* r = Wb + (base + t) * NN;
#pragma unroll
                for (int c = 0; c < 9; ++c)
                    w[t][c] = pk(r[pA[c]], (pB[c] < 0) ? 0.f : r[pB[c]]);
            } else {
#pragma unroll
                for (int c = 0; c < 9; ++c) w[t][c] = 0u;
            }
        }
    }

    // ---- replicated packed state + own-slot f32 state ----
    uint32_t s2[9];
    {
        float st[17];
#pragma unroll
        for (int j = 0; j < NN; ++j) st[j] = state0[(size_t)b * NN + j];
#pragma unroll
        for (int c = 0; c < 9; ++c)
            s2[c] = pk(st[pA[c]], (pB[c] < 0) ? 0.f : st[pB[c]]);
    }
    float sOwn[5];
#pragma unroll
    for (int t = 0; t < 5; ++t)
        sOwn[t] = (t < nrows) ? state0[(size_t)b * NN + base + t] : 0.f;

    // ---- per-lane constants ----
    float addc[5], pdv[5], gP[4], gm[4];
#pragma unroll
    for (int t = 0; t < 5; ++t) { addc[t] = 0.f; pdv[t] = 0.f; }
#pragma unroll
    for (int t = 0; t < 4; ++t) { gP[t] = 0.f; gm[t] = 1.f; }
    if (l4 < 2) {                       // needs rows (lanes 0,1,4,5)
#pragma unroll
        for (int t = 0; t < 5; ++t) {
            if (t < nrows) {
                float pv = P[(size_t)b * NN + base + t];
                addc[t] = isE ? fmaxf(pv, 0.f) : fmaxf(-pv, 0.f);
            }
        }
    } else if (isActs) {                // acts rows (lanes 2,6)
#pragma unroll
        for (int t = 0; t < 4; ++t) {
            gP[t] = P[(size_t)b * NN + 13 + t];
            if (isE) gm[t] = feas[(size_t)b * 4 + t];
        }
    } else if (isE) {                   // vals E-lane (lane 3): direct drive
#pragma unroll
        for (int t = 0; t < 4; ++t)
            pdv[t] = P[(size_t)b * NN + 13 + t];
    }

    const float lo = (l4 == 3) ? -1.f : 0.f;
    const float dtv = t_eval[1] - t_eval[0];
    const float k1 = dtv * 1.25f;                 // dt / TAU
    const float C  = -1.0820212806667226f;        // -0.75 * log2(e)

    // ---- write step 0 (lanes 0-3 only) ----
    if (isE) {
        float* op = out + (size_t)b * NN + base;
#pragma unroll
        for (int t = 0; t < 5; ++t)
            if (t < nrows) op[t] = sOwn[t];
    }
    float* outp = out + (size_t)BATCH * NN + (size_t)b * NN + base;

#pragma unroll 1
    for (int st = 1; st < TT; ++st) {
        // ---- matvec: 5 rows x 9 dot2 (own side), uniform relu ----
        float R[5];
#pragma unroll
        for (int t = 0; t < 5; ++t) {
            float a = 0.f;
#pragma unroll
            for (int c = 0; c < 9; ++c) a = dot2(w[t][c], s2[c], a);
            R[t] = fmaxf(a, 0.f);
        }

        // ---- uniform transform (gates/lateral via selects, no branches) ----
        float Rp[5];
        {
            const float v0 = lo16(s2[7]), v1 = hi16(s2[7]);
            const float v2 = lo16(s2[8]), v3 = hi16(s2[8]);
            const float a0 = lo16(s2[5]), a1 = hi16(s2[5]);
            const float a2 = lo16(s2[6]), a3 = hi16(s2[6]);
            const float sum_acts = (a0 + a1) + (a2 + a3);
            const float v13[4] = {v0, v1, v2, v3};
            const float av[4]  = {a0, a1, a2, a3};
#pragma unroll
            for (int t = 0; t < 4; ++t) {
                float v  = v13[t] + gP[t];
                float e1 = __builtin_amdgcn_exp2f(C * v);   // e^(-0.75 v)
                float t0 = isE ? e1 : 1.0f;
                float r  = __builtin_amdgcn_rcpf(fmaf(e1, t0, 1.0f));
                float g  = isE ? r : e1 * r;                // sig(1.5v) or sig(-.75v)
                float gate = isActs ? g * gm[t] : 1.0f;
                float os  = sum_acts - av[t];
                float lat = fmaf(-0.9f, __builtin_amdgcn_rcpf(0.3f + os), 3.0f);
                float addv = isLat ? lat : addc[t];
                Rp[t] = fmaf(gate, R[t], addv);
            }
            Rp[4] = R[4] + addc[4];
        }

        // ---- ship I from lanes 4-7 to lanes 0-3 (lane^4) ----
        float Iv[5];
#pragma unroll
        for (int t = 0; t < 5; ++t) Iv[t] = swzf<SWZ_X4>(Rp[t]);

        // ---- shunting update + clip (meaningful on lanes 0-3) ----
#pragma unroll
        for (int t = 0; t < 5; ++t) {
            float s  = sOwn[t];
            float d  = fmaf(1.f - s, Rp[t], fmaf(-0.15f, s, pdv[t]));
            d        = fmaf(-(0.1f + s), Iv[t], d);
            float raw = fmaf(k1, d, s);
            sOwn[t] = fminf(fmaxf(raw, lo), 1.f);
        }

        // ---- pack own block, broadcast lanes 0-3 -> all 8 ----
        uint32_t p0 = pk(sOwn[0], sOwn[1]);
        uint32_t p1 = pk(sOwn[2], sOwn[3]);
        uint32_t p2 = pk(sOwn[4], 0.f);
        s2[0] = swz<SWZ_B0>(p0); s2[1] = swz<SWZ_B0>(p1); s2[2] = swz<SWZ_B0>(p2);
        s2[3] = swz<SWZ_B1>(p0); s2[4] = swz<SWZ_B1>(p1);
        s2[5] = swz<SWZ_B2>(p0); s2[6] = swz<SWZ_B2>(p1);
        s2[7] = swz<SWZ_B3>(p0); s2[8] = swz<SWZ_B3>(p1);

        // ---- store (lanes 0-3) ----
        if (isE) {
#pragma unroll
            for (int t = 0; t < 5; ++t)
                if (t < nrows) outp[t] = sOwn[t];
        }
        outp += (size_t)BATCH * NN;
    }
}

extern "C" void kernel_launch(void* const* d_in, const int* in_sizes, int n_in,
                              void* d_out, int out_size, void* d_ws, size_t ws_size,
                              hipStream_t stream) {
    const float* state0 = (const float*)d_in[0];
    const float* Wpos   = (const float*)d_in[1];
    const float* Wneg   = (const float*)d_in[2];
    const float* feasv  = (const float*)d_in[3];
    const float* P      = (const float*)d_in[4];
    const float* t_eval = (const float*)d_in[5];
    float* out = (float*)d_out;

    dim3 grid(BATCH * 8 / 256), block(256);
    hipLaunchKernelGGL(hotco_kernel, grid, block, 0, stream,
                       state0, Wpos, Wneg, feasv, P, t_eval, out);
}

// Round 5
// 155.842 us; speedup vs baseline: 1.2941x; 1.2941x over previous
//
#include <hip/hip_runtime.h>
#include <stdint.h>

// Grossberg shunting ODE, 127 Euler steps, BATCH=32768, N=17.
// R3 structure (4 lanes/item, W f16-packed register-resident, dot2 matvec)
// + DPP quad_perm state broadcast (no DS pipe, no lgkmcnt stall)
// + float4 stores, float4 W loads, trimmed constant registers.

typedef _Float16 h2 __attribute__((ext_vector_type(2)));
typedef __fp16 h2raw __attribute__((ext_vector_type(2)));
typedef float f4a __attribute__((ext_vector_type(4), aligned(4)));

static constexpr int BATCH = 32768;
static constexpr int NN = 17;
static constexpr int TT = 128;

__device__ __forceinline__ uint32_t pk(float a, float b) {
    h2raw h = __builtin_amdgcn_cvt_pkrtz(a, b);
    return __builtin_bit_cast(uint32_t, h);
}
__device__ __forceinline__ float dot2(uint32_t a, uint32_t b, float c) {
    return __builtin_amdgcn_fdot2(__builtin_bit_cast(h2, a),
                                  __builtin_bit_cast(h2, b), c, false);
}
__device__ __forceinline__ float lo16(uint32_t u) {
    h2 h = __builtin_bit_cast(h2, u); return (float)h.x;
}
__device__ __forceinline__ float hi16(uint32_t u) {
    h2 h = __builtin_bit_cast(h2, u); return (float)h.y;
}
// DPP quad_perm broadcast of quad-lane K to all 4 lanes of the quad.
// Pure VALU (no DS pipe, no lgkmcnt).
template <int K>
__device__ __forceinline__ uint32_t qbcast(uint32_t v) {
    constexpr int ctrl = K * 0x55;   // quad_perm [K,K,K,K]
    return (uint32_t)__builtin_amdgcn_update_dpp(0, (int)v, ctrl, 0xF, 0xF, false);
}

__global__ __launch_bounds__(256, 2) void hotco_kernel(
    const float* __restrict__ state0,
    const float* __restrict__ Wpos,
    const float* __restrict__ Wneg,
    const float* __restrict__ feas,
    const float* __restrict__ P,
    const float* __restrict__ t_eval,
    float* __restrict__ out)
{
    const int tid = blockIdx.x * blockDim.x + threadIdx.x;
    const int lane4 = tid & 3;     // quad lane == DPP quad position
    const int b = tid >> 2;
    if (b >= BATCH) return;

    // lane0: rows 0-4 (needs), lane1: 5-8 (needs), lane2: 9-12 (acts), lane3: 13-16 (vals)
    const int base = (lane4 == 0) ? 0 : (4 * lane4 + 1);
    const int nrows = (lane4 == 0) ? 5 : 4;

    // ---- W into registers, packed f16 pairs; float4-vectorized loads ----
    // pair grouping: (0,1)(2,3)(4,-)(5,6)(7,8)(9,10)(11,12)(13,14)(15,16)
    uint32_t w[5][9];
    {
        const float* wpb = Wpos + (size_t)b * (NN * NN);
        const float* wnb = Wneg + (size_t)b * (NN * NN);
#pragma unroll
        for (int t = 0; t < 5; ++t) {
            const int half = (t < nrows) ? 0 : 1;   // t==4 on lanes 1-3: duplicate row, zeroed
            const float* r = (half ? wnb : wpb) + (base + ((t < nrows) ? t : 0)) * NN;
            (void)r;
        }
        // E rows then padding logic, done explicitly below.
#pragma unroll
        for (int t = 0; t < 5; ++t) {
            if (t < nrows) {
                const float* rp = wpb + (base + t) * NN;
                f4a q0 = *(const f4a*)(rp + 0);
                f4a q1 = *(const f4a*)(rp + 4);
                f4a q2 = *(const f4a*)(rp + 8);
                f4a q3 = *(const f4a*)(rp + 12);
                float e16 = rp[16];
                w[t][0] = pk(q0.x, q0.y);
                w[t][1] = pk(q0.z, q0.w);
                w[t][2] = pk(q1.x, 0.f);
                w[t][3] = pk(q1.y, q1.z);
                w[t][4] = pk(q1.w, q2.x);
                w[t][5] = pk(q2.y, q2.z);
                w[t][6] = pk(q2.w, q3.x);
                w[t][7] = pk(q3.y, q3.z);
                w[t][8] = pk(q3.w, e16);
            } else {
#pragma unroll
                for (int c = 0; c < 9; ++c) w[t][c] = 0u;
            }
        }
    }
    uint32_t wn[5][9];
    {
        const float* wnb = Wneg + (size_t)b * (NN * NN);
#pragma unroll
        for (int t = 0; t < 5; ++t) {
            if (t < nrows) {
                const float* rn = wnb + (base + t) * NN;
                f4a q0 = *(const f4a*)(rn + 0);
                f4a q1 = *(const f4a*)(rn + 4);
                f4a q2 = *(const f4a*)(rn + 8);
                f4a q3 = *(const f4a*)(rn + 12);
                float e16 = rn[16];
                wn[t][0] = pk(q0.x, q0.y);
                wn[t][1] = pk(q0.z, q0.w);
                wn[t][2] = pk(q1.x, 0.f);
                wn[t][3] = pk(q1.y, q1.z);
                wn[t][4] = pk(q1.w, q2.x);
                wn[t][5] = pk(q2.y, q2.z);
                wn[t][6] = pk(q2.w, q3.x);
                wn[t][7] = pk(q3.y, q3.z);
                wn[t][8] = pk(q3.w, e16);
            } else {
#pragma unroll
                for (int c = 0; c < 9; ++c) wn[t][c] = 0u;
            }
        }
    }

    // ---- initial replicated packed state + own f32 slots ----
    uint32_t s2[9];
    {
        const float* sb = state0 + (size_t)b * NN;
        float st[17];
#pragma unroll
        for (int j = 0; j < NN; ++j) st[j] = sb[j];
        s2[0] = pk(st[0], st[1]);   s2[1] = pk(st[2], st[3]);
        s2[2] = pk(st[4], 0.f);     s2[3] = pk(st[5], st[6]);
        s2[4] = pk(st[7], st[8]);   s2[5] = pk(st[9], st[10]);
        s2[6] = pk(st[11], st[12]); s2[7] = pk(st[13], st[14]);
        s2[8] = pk(st[15], st[16]);
    }
    float sOwn[5];
#pragma unroll
    for (int t = 0; t < 5; ++t)
        sOwn[t] = (t < nrows) ? state0[(size_t)b * NN + base + t] : 0.f;

    // ---- per-lane-class constants (disjoint reuse: 14 regs total) ----
    // needs lanes (0,1): cA = relu(P), cB = relu(-P)
    // acts lane  (2)   : cA = feasibility, cB = gate perturbation P[13+t]
    // vals lane  (3)   : cA = 0, cB = 0; pdv = P[13+t]
    float cA[5], cB[5], pdv[4];
#pragma unroll
    for (int t = 0; t < 5; ++t) { cA[t] = 0.f; cB[t] = 0.f; }
#pragma unroll
    for (int t = 0; t < 4; ++t) pdv[t] = 0.f;
    if (lane4 < 2) {
#pragma unroll
        for (int t = 0; t < 5; ++t) {
            if (t < nrows) {
                float pv = P[(size_t)b * NN + base + t];
                cA[t] = fmaxf(pv, 0.f);
                cB[t] = fmaxf(-pv, 0.f);
            }
        }
    } else if (lane4 == 2) {
#pragma unroll
        for (int t = 0; t < 4; ++t) {
            cA[t] = feas[(size_t)b * 4 + t];
            cB[t] = P[(size_t)b * NN + 13 + t];
        }
    } else {
#pragma unroll
        for (int t = 0; t < 4; ++t)
            pdv[t] = P[(size_t)b * NN + 13 + t];
    }

    const float lo = (lane4 == 3) ? -1.f : 0.f;
    const float dtv = t_eval[1] - t_eval[0];
    const float k1 = dtv * 1.25f;                 // dt / TAU
    const float C  = -1.0820212806667226f;        // -0.75 * log2(e)

    // ---- write step 0 ----
    {
        float* op = out + (size_t)b * NN + base;
        f4a v0; v0.x = sOwn[0]; v0.y = sOwn[1]; v0.z = sOwn[2]; v0.w = sOwn[3];
        *(f4a*)op = v0;
        if (nrows == 5) op[4] = sOwn[4];
    }
    float* outp = out + (size_t)BATCH * NN + (size_t)b * NN + base;

#pragma unroll 1
    for (int st = 1; st < TT; ++st) {
        // ---- matvec: 2 x (5 rows x 9 dot2), uniform relu ----
        float E5[5], I5[5];
#pragma unroll
        for (int t = 0; t < 5; ++t) {
            float ae = 0.f, ai = 0.f;
#pragma unroll
            for (int c = 0; c < 9; ++c) {
                ae = dot2(w[t][c], s2[c], ae);
                ai = dot2(wn[t][c], s2[c], ai);
            }
            E5[t] = fmaxf(ae, 0.f);   // relu(g*x) = g*relu(x), g>0
            I5[t] = fmaxf(ai, 0.f);
        }

        // ---- class transform (lane2 divergent; others cheap adds) ----
        if (lane4 == 2) {
            const float sum_acts = sOwn[0] + sOwn[1] + sOwn[2] + sOwn[3];
            const float v13[4] = { lo16(s2[7]), hi16(s2[7]), lo16(s2[8]), hi16(s2[8]) };
#pragma unroll
            for (int t = 0; t < 4; ++t) {
                float v  = v13[t] + cB[t];
                float e1 = __builtin_amdgcn_exp2f(C * v);              // e^(-0.75 v)
                float ge = __builtin_amdgcn_rcpf(fmaf(e1, e1, 1.f));   // sigmoid(1.5v)
                float gi = e1 * __builtin_amdgcn_rcpf(1.f + e1);       // sigmoid(-0.75v)
                E5[t] = ge * E5[t] * cA[t];
                float os  = sum_acts - sOwn[t];
                float lat = fmaf(-0.9f, __builtin_amdgcn_rcpf(0.3f + os), 3.0f);
                I5[t] = fmaf(gi, I5[t], lat);
            }
            E5[4] = 0.f; I5[4] = 0.f;
        } else {
#pragma unroll
            for (int t = 0; t < 5; ++t) { E5[t] += cA[t]; I5[t] += cB[t]; }
        }

        // ---- shunting update + clip ----
#pragma unroll
        for (int t = 0; t < 5; ++t) {
            float s  = sOwn[t];
            float d0 = (t < 4) ? fmaf(-0.15f, s, pdv[t]) : (-0.15f * s);
            float d1 = fmaf(1.f - s, E5[t], d0);
            float d2 = fmaf(-(0.1f + s), I5[t], d1);
            float raw = fmaf(k1, d2, s);
            sOwn[t] = fminf(fmaxf(raw, lo), 1.f);
        }

        // ---- pack own block, DPP-broadcast across the quad (no DS) ----
        uint32_t p0 = pk(sOwn[0], sOwn[1]);
        uint32_t p1 = pk(sOwn[2], sOwn[3]);
        uint32_t p2 = pk(sOwn[4], 0.f);
        s2[0] = qbcast<0>(p0); s2[1] = qbcast<0>(p1); s2[2] = qbcast<0>(p2);
        s2[3] = qbcast<1>(p0); s2[4] = qbcast<1>(p1);
        s2[5] = qbcast<2>(p0); s2[6] = qbcast<2>(p1);
        s2[7] = qbcast<3>(p0); s2[8] = qbcast<3>(p1);

        // ---- store (float4 + optional scalar) ----
        {
            f4a v0; v0.x = sOwn[0]; v0.y = sOwn[1]; v0.z = sOwn[2]; v0.w = sOwn[3];
            *(f4a*)outp = v0;
            if (nrows == 5) outp[4] = sOwn[4];
        }
        outp += (size_t)BATCH * NN;
    }
}

extern "C" void kernel_launch(void* const* d_in, const int* in_sizes, int n_in,
                              void* d_out, int out_size, void* d_ws, size_t ws_size,
                              hipStream_t stream) {
    const float* state0 = (const float*)d_in[0];
    const float* Wpos   = (const float*)d_in[1];
    const float* Wneg   = (const float*)d_in[2];
    const float* feasv  = (const float*)d_in[3];
    const float* P      = (const float*)d_in[4];
    const float* t_eval = (const float*)d_in[5];
    float* out = (float*)d_out;

    dim3 grid(BATCH * 4 / 256), block(256);
    hipLaunchKernelGGL(hotco_kernel, grid, block, 0, stream,
                       state0, Wpos, Wneg, feasv, P, t_eval, out);
}

// Round 6
// 150.943 us; speedup vs baseline: 1.3361x; 1.0325x over previous
//
#include <hip/hip_runtime.h>
#include <stdint.h>

// Grossberg shunting ODE, 127 Euler steps, BATCH=32768, N=17.
// R3 structure: 4 lanes/item, W f16-packed, dot2 matvec, 16 items/wave.
// R6: force W register-residency — amdgpu_waves_per_eu(2,2) for the full
// 256-reg budget + asm pins so W cannot be rematerialized from memory.
// State broadcast via DPP quad_perm (pure VALU).

typedef _Float16 h2 __attribute__((ext_vector_type(2)));
typedef __fp16 h2raw __attribute__((ext_vector_type(2)));
typedef float f4a __attribute__((ext_vector_type(4), aligned(4)));

static constexpr int BATCH = 32768;
static constexpr int NN = 17;
static constexpr int TT = 128;

__device__ __forceinline__ uint32_t pk(float a, float b) {
    h2raw h = __builtin_amdgcn_cvt_pkrtz(a, b);
    return __builtin_bit_cast(uint32_t, h);
}
__device__ __forceinline__ float dot2(uint32_t a, uint32_t b, float c) {
    return __builtin_amdgcn_fdot2(__builtin_bit_cast(h2, a),
                                  __builtin_bit_cast(h2, b), c, false);
}
__device__ __forceinline__ float lo16(uint32_t u) {
    h2 h = __builtin_bit_cast(h2, u); return (float)h.x;
}
__device__ __forceinline__ float hi16(uint32_t u) {
    h2 h = __builtin_bit_cast(h2, u); return (float)h.y;
}
template <int K>
__device__ __forceinline__ uint32_t qbcast(uint32_t v) {
    constexpr int ctrl = K * 0x55;   // quad_perm [K,K,K,K]
    return (uint32_t)__builtin_amdgcn_update_dpp(0, (int)v, ctrl, 0xF, 0xF, false);
}

__global__ __launch_bounds__(256)
__attribute__((amdgpu_waves_per_eu(2, 2)))
void hotco_kernel(
    const float* __restrict__ state0,
    const float* __restrict__ Wpos,
    const float* __restrict__ Wneg,
    const float* __restrict__ feas,
    const float* __restrict__ P,
    const float* __restrict__ t_eval,
    float* __restrict__ out)
{
    const int tid = blockIdx.x * blockDim.x + threadIdx.x;
    const int lane4 = tid & 3;     // DPP quad position
    const int b = tid >> 2;

    // lane0: rows 0-4 (needs), lane1: 5-8 (needs), lane2: 9-12 (acts), lane3: 13-16 (vals)
    const int base = (lane4 == 0) ? 0 : (4 * lane4 + 1);
    const int nrows = (lane4 == 0) ? 5 : 4;

    // pair grouping: (0,1)(2,3)(4,-)(5,6)(7,8)(9,10)(11,12)(13,14)(15,16)
    constexpr int pA[9] = {0, 2, 4, 5, 7, 9, 11, 13, 15};
    constexpr int pB[9] = {1, 3, -1, 6, 8, 10, 12, 14, 16};

    // ---- W into registers, packed f16 pairs ----
    uint32_t w[5][9], wn[5][9];
    {
        const float* wpb = Wpos + (size_t)b * (NN * NN);
        const float* wnb = Wneg + (size_t)b * (NN * NN);
#pragma unroll
        for (int t = 0; t < 5; ++t) {
            if (t < nrows) {
                const float* rp = wpb + (base + t) * NN;
                const float* rn = wnb + (base + t) * NN;
#pragma unroll
                for (int c = 0; c < 9; ++c) {
                    float a2 = (pB[c] < 0) ? 0.f : rp[pB[c]];
                    float b2 = (pB[c] < 0) ? 0.f : rn[pB[c]];
                    w[t][c]  = pk(rp[pA[c]], a2);
                    wn[t][c] = pk(rn[pA[c]], b2);
                }
            } else {
#pragma unroll
                for (int c = 0; c < 9; ++c) { w[t][c] = 0u; wn[t][c] = 0u; }
            }
        }
    }

    // ---- per-lane-class constants ----
    float cA[5], cB[5], pdv[4];
#pragma unroll
    for (int t = 0; t < 5; ++t) { cA[t] = 0.f; cB[t] = 0.f; }
#pragma unroll
    for (int t = 0; t < 4; ++t) pdv[t] = 0.f;
    if (lane4 < 2) {
#pragma unroll
        for (int t = 0; t < 5; ++t) {
            if (t < nrows) {
                float pv = P[(size_t)b * NN + base + t];
                cA[t] = fmaxf(pv, 0.f);
                cB[t] = fmaxf(-pv, 0.f);
            }
        }
    } else if (lane4 == 2) {
#pragma unroll
        for (int t = 0; t < 4; ++t) {
            cA[t] = feas[(size_t)b * 4 + t];
            cB[t] = P[(size_t)b * NN + 13 + t];
        }
    } else {
#pragma unroll
        for (int t = 0; t < 4; ++t)
            pdv[t] = P[(size_t)b * NN + 13 + t];
    }

    // ---- pin invariants into arch VGPRs: def becomes the asm, so the
    // compiler can neither rematerialize nor reload them in the loop ----
#pragma unroll
    for (int t = 0; t < 5; ++t)
#pragma unroll
        for (int c = 0; c < 9; ++c) {
            asm volatile("" : "+v"(w[t][c]));
            asm volatile("" : "+v"(wn[t][c]));
        }
#pragma unroll
    for (int t = 0; t < 5; ++t) {
        asm volatile("" : "+v"(cA[t]));
        asm volatile("" : "+v"(cB[t]));
    }
#pragma unroll
    for (int t = 0; t < 4; ++t)
        asm volatile("" : "+v"(pdv[t]));

    // ---- initial replicated packed state + own f32 slots ----
    uint32_t s2[9];
    {
        const float* sb = state0 + (size_t)b * NN;
        float st[17];
#pragma unroll
        for (int j = 0; j < NN; ++j) st[j] = sb[j];
        s2[0] = pk(st[0], st[1]);   s2[1] = pk(st[2], st[3]);
        s2[2] = pk(st[4], 0.f);     s2[3] = pk(st[5], st[6]);
        s2[4] = pk(st[7], st[8]);   s2[5] = pk(st[9], st[10]);
        s2[6] = pk(st[11], st[12]); s2[7] = pk(st[13], st[14]);
        s2[8] = pk(st[15], st[16]);
    }
    float sOwn[5];
#pragma unroll
    for (int t = 0; t < 5; ++t)
        sOwn[t] = (t < nrows) ? state0[(size_t)b * NN + base + t] : 0.f;

    const float lo = (lane4 == 3) ? -1.f : 0.f;
    const float dtv = t_eval[1] - t_eval[0];
    const float k1 = dtv * 1.25f;                 // dt / TAU
    const float C  = -1.0820212806667226f;        // -0.75 * log2(e)

    // ---- write step 0 ----
    {
        float* op = out + (size_t)b * NN + base;
        f4a v0; v0.x = sOwn[0]; v0.y = sOwn[1]; v0.z = sOwn[2]; v0.w = sOwn[3];
        *(f4a*)op = v0;
        if (nrows == 5) op[4] = sOwn[4];
    }
    float* outp = out + (size_t)BATCH * NN + (size_t)b * NN + base;

#pragma unroll 1
    for (int st = 1; st < TT; ++st) {
        // ---- matvec: 2 x (5 rows x 9 dot2), uniform relu ----
        float E5[5], I5[5];
#pragma unroll
        for (int t = 0; t < 5; ++t) {
            float ae = 0.f, ai = 0.f;
#pragma unroll
            for (int c = 0; c < 9; ++c) {
                ae = dot2(w[t][c], s2[c], ae);
                ai = dot2(wn[t][c], s2[c], ai);
            }
            E5[t] = fmaxf(ae, 0.f);   // relu(g*x) = g*relu(x), g>0
            I5[t] = fmaxf(ai, 0.f);
        }

        // ---- class transform (lane2 masked; others cheap adds) ----
        if (lane4 == 2) {
            const float sum_acts = sOwn[0] + sOwn[1] + sOwn[2] + sOwn[3];
            const float v13[4] = { lo16(s2[7]), hi16(s2[7]), lo16(s2[8]), hi16(s2[8]) };
#pragma unroll
            for (int t = 0; t < 4; ++t) {
                float v  = v13[t] + cB[t];
                float e1 = __builtin_amdgcn_exp2f(C * v);              // e^(-0.75 v)
                float ge = __builtin_amdgcn_rcpf(fmaf(e1, e1, 1.f));   // sigmoid(1.5v)
                float gi = e1 * __builtin_amdgcn_rcpf(1.f + e1);       // sigmoid(-0.75v)
                E5[t] = ge * E5[t] * cA[t];
                float os  = sum_acts - sOwn[t];
                float lat = fmaf(-0.9f, __builtin_amdgcn_rcpf(0.3f + os), 3.0f);
                I5[t] = fmaf(gi, I5[t], lat);
            }
            E5[4] = 0.f; I5[4] = 0.f;
        } else {
#pragma unroll
            for (int t = 0; t < 5; ++t) { E5[t] += cA[t]; I5[t] += cB[t]; }
        }

        // ---- shunting update + clip ----
#pragma unroll
        for (int t = 0; t < 5; ++t) {
            float s  = sOwn[t];
            float d0 = (t < 4) ? fmaf(-0.15f, s, (lane4 == 3) ? pdv[t] : 0.f)
                               : (-0.15f * s);
            float d1 = fmaf(1.f - s, E5[t], d0);
            float d2 = fmaf(-(0.1f + s), I5[t], d1);
            float raw = fmaf(k1, d2, s);
            sOwn[t] = fminf(fmaxf(raw, lo), 1.f);
        }

        // ---- pack own block, DPP-broadcast across the quad ----
        uint32_t p0 = pk(sOwn[0], sOwn[1]);
        uint32_t p1 = pk(sOwn[2], sOwn[3]);
        uint32_t p2 = pk(sOwn[4], 0.f);
        s2[0] = qbcast<0>(p0); s2[1] = qbcast<0>(p1); s2[2] = qbcast<0>(p2);
        s2[3] = qbcast<1>(p0); s2[4] = qbcast<1>(p1);
        s2[5] = qbcast<2>(p0); s2[6] = qbcast<2>(p1);
        s2[7] = qbcast<3>(p0); s2[8] = qbcast<3>(p1);

        // ---- store (float4 + optional scalar) ----
        {
            f4a v0; v0.x = sOwn[0]; v0.y = sOwn[1]; v0.z = sOwn[2]; v0.w = sOwn[3];
            *(f4a*)outp = v0;
            if (nrows == 5) outp[4] = sOwn[4];
        }
        outp += (size_t)BATCH * NN;
    }
}

extern "C" void kernel_launch(void* const* d_in, const int* in_sizes, int n_in,
                              void* d_out, int out_size, void* d_ws, size_t ws_size,
                              hipStream_t stream) {
    const float* state0 = (const float*)d_in[0];
    const float* Wpos   = (const float*)d_in[1];
    const float* Wneg   = (const float*)d_in[2];
    const float* feasv  = (const float*)d_in[3];
    const float* P      = (const float*)d_in[4];
    const float* t_eval = (const float*)d_in[5];
    float* out = (float*)d_out;

    dim3 grid(BATCH * 4 / 256), block(256);
    hipLaunchKernelGGL(hotco_kernel, grid, block, 0, stream,
                       state0, Wpos, Wneg, feasv, P, t_eval, out);
}